// Round 3
// baseline (293.492 us; speedup 1.0000x reference)
//
#include <hip/hip_runtime.h>
#include <math.h>

#define DD 160
#define HH 160
#define WW 160
#define NB 2
#define SLICE (HH * WW)        // 25600
#define NV 51200               // NB*160*160 vectors per reduction type
#define Dt 4                   // d's per block
#define NDC 40                 // d-chunks (160/Dt)
#define NHC 10                 // h-chunks
#define HCS 16                 // rows per h-chunk
#define NTHR 320               // 8 groups x 40 float4-lanes

static constexpr float EPS = 1e-12f;
static constexpr float SCALE = -1.0f / 960.0f;  // -(six cos sums)/(160*2*3)

#define ELEM(v, j) ((j) == 0 ? (v).x : ((j) == 1 ? (v).y : ((j) == 2 ? (v).z : (v).w)))

// Zero the 1.23 MB atomic along-D accumulator array + the output scalar.
// 6*NV floats = 76800 float4 -> exactly 300 blocks x 256 threads.
__global__ __launch_bounds__(256) void zeroP(float4* __restrict__ pD4,
                                             float* __restrict__ out) {
  const int i = blockIdx.x * 256 + threadIdx.x;
  pD4[i] = make_float4(0.0f, 0.0f, 0.0f, 0.0f);
  if (i == 0) out[0] = 0.0f;
}

// ---------------------------------------------------------------------------
// mainS2: one pass over the inputs.
//  - alongW cosines (gx,gy): completed in-block -> accCos -> one atomic.
//  - alongH partials (gx,gz): LDS-reduced over 8 groups -> pH[10][6][NV].
//  - alongD partials (gy,gz): 48 persistent VGPR accumulators across the 4
//    d-phases, then 48 device-scope atomicAdds into pD2[6][NV] (1.23 MB,
//    cache-resident, ~40 adds/address over the kernel lifetime). This
//    replaces round-2's gradD kernel (which re-read the full input) and
//    round-0's 49 MB partial spill.
//  d-neighbor slice loads are software-prefetched one phase ahead.
// ---------------------------------------------------------------------------
__global__ __launch_bounds__(NTHR, 2) void mainS2(const float* __restrict__ f,
                                                  const float* __restrict__ t,
                                                  float* __restrict__ pH,
                                                  float* __restrict__ pD2,
                                                  float* __restrict__ out) {
  __shared__ float sw[HCS * 40 * 7];    // per-(row,lane) alongW partials
  __shared__ float sh[8 * 40 * 25];     // per-(group,lane) alongH partials
  __shared__ float red[HCS][6];
  __shared__ float cpad[HCS];
  const int tid = threadIdx.x;
  const int g = tid / 40;               // group 0..7
  const int l = tid % 40;               // float4-lane
  const int w = 4 * l;
  const int wn = (w + 4 < WW) ? (w + 4) : (WW - 1);  // clamp -> gz[3]=0 at w=159
  const int hc = blockIdx.x % NHC;
  const int t2 = blockIdx.x / NHC;
  const int dc = t2 % NDC;
  const int b  = t2 / NDC;
  const int d0 = dc * Dt;
  const int r0 = hc * HCS + g * 2;      // thread's two consecutive rows
  const int r1 = r0 + 1;
  const int r2 = (r1 + 1 < HH) ? (r1 + 1) : (HH - 1);  // clamp -> gy=0 at h=159
  const float* fb = f + (size_t)b * DD * SLICE;
  const float* tb = t + (size_t)b * DD * SLICE;

  // chain selves: slice d0, rows r0,r1 (+ wn scalars)
  float4 S0f = *(const float4*)(fb + (size_t)d0 * SLICE + r0 * WW + w);
  float4 S0t = *(const float4*)(tb + (size_t)d0 * SLICE + r0 * WW + w);
  float4 S1f = *(const float4*)(fb + (size_t)d0 * SLICE + r1 * WW + w);
  float4 S1t = *(const float4*)(tb + (size_t)d0 * SLICE + r1 * WW + w);
  float s0fz = (fb + (size_t)d0 * SLICE + r0 * WW)[wn];
  float s0tz = (tb + (size_t)d0 * SLICE + r0 * WW)[wn];
  float s1fz = (fb + (size_t)d0 * SLICE + r1 * WW)[wn];
  float s1tz = (tb + (size_t)d0 * SLICE + r1 * WW)[wn];
  // prefetched d-neighbor slice d0+1 (d0 <= 156, always in range)
  const float* fN0 = fb + (size_t)(d0 + 1) * SLICE;
  const float* tN0 = tb + (size_t)(d0 + 1) * SLICE;
  float4 D0f = *(const float4*)(fN0 + r0 * WW + w);
  float4 D0t = *(const float4*)(tN0 + r0 * WW + w);
  float4 D1f = *(const float4*)(fN0 + r1 * WW + w);
  float4 D1t = *(const float4*)(tN0 + r1 * WW + w);
  float d0fz = (fN0 + r0 * WW)[wn], d0tz = (tN0 + r0 * WW)[wn];
  float d1fz = (fN0 + r1 * WW)[wn], d1tz = (tN0 + r1 * WW)[wn];

  float aD[48];                         // alongD (gy,gz) persistent accumulators
#pragma unroll
  for (int c = 0; c < 48; ++c) aD[c] = 0.0f;
  float accCos = 0.0f;

#pragma unroll
  for (int p = 0; p < Dt; ++p) {
    const int d = d0 + p;
    const float* fS = fb + (size_t)d * SLICE;
    const float* tS = tb + (size_t)d * SLICE;
    // same-slice row r2 (L1/L2 hit: neighbor group loaded it last phase)
    const float4 Hf = *(const float4*)(fS + r2 * WW + w);
    const float4 Ht = *(const float4*)(tS + r2 * WW + w);
    // prefetch NEXT phase's d-neighbor slice (the cold loads)
    float4 nD0f = {0, 0, 0, 0}, nD0t = {0, 0, 0, 0};
    float4 nD1f = {0, 0, 0, 0}, nD1t = {0, 0, 0, 0};
    float n0fz = 0.f, n0tz = 0.f, n1fz = 0.f, n1tz = 0.f;
    if (p < Dt - 1) {
      const int nd = d + 1;
      const int ndn = (nd + 1 < DD) ? (nd + 1) : nd;  // clamp -> gx=0 at d=159
      const float* fN = fb + (size_t)ndn * SLICE;
      const float* tN = tb + (size_t)ndn * SLICE;
      nD0f = *(const float4*)(fN + r0 * WW + w);
      nD0t = *(const float4*)(tN + r0 * WW + w);
      nD1f = *(const float4*)(fN + r1 * WW + w);
      nD1t = *(const float4*)(tN + r1 * WW + w);
      n0fz = (fN + r0 * WW)[wn]; n0tz = (tN + r0 * WW)[wn];
      n1fz = (fN + r1 * WW)[wn]; n1tz = (tN + r1 * WW)[wn];
    }

    float aH[24];
#pragma unroll
    for (int c = 0; c < 24; ++c) aH[c] = 0.0f;

    // ---- row r0: gx = D0-S0, gy = S1-S0, gz = shift(S0) ----
    {
      float xd = 0, xf = 0, xt = 0, yd = 0, yf = 0, yt = 0;
#pragma unroll
      for (int j = 0; j < 4; ++j) {
        const float f0 = ELEM(S0f, j), t0 = ELEM(S0t, j);
        const float gxf = ELEM(D0f, j) - f0, gxt = ELEM(D0t, j) - t0;
        const float gyf = ELEM(S1f, j) - f0, gyt = ELEM(S1t, j) - t0;
        const float fnx = (j < 3) ? ELEM(S0f, j + 1) : s0fz;
        const float tnx = (j < 3) ? ELEM(S0t, j + 1) : s0tz;
        const float gzf = fnx - f0, gzt = tnx - t0;
        xd += gxf * gxt; xf += gxf * gxf; xt += gxt * gxt;
        yd += gyf * gyt; yf += gyf * gyf; yt += gyt * gyt;
        aH[j * 6 + 0] += gxf * gxt; aH[j * 6 + 1] += gxf * gxf; aH[j * 6 + 2] += gxt * gxt;
        aH[j * 6 + 3] += gzf * gzt; aH[j * 6 + 4] += gzf * gzf; aH[j * 6 + 5] += gzt * gzt;
        aD[j * 6 + 0] += gyf * gyt; aD[j * 6 + 1] += gyf * gyf; aD[j * 6 + 2] += gyt * gyt;
        aD[j * 6 + 3] += gzf * gzt; aD[j * 6 + 4] += gzf * gzf; aD[j * 6 + 5] += gzt * gzt;
      }
      float* s = &sw[((g * 2 + 0) * 40 + l) * 7];
      s[0] = xd; s[1] = xf; s[2] = xt; s[3] = yd; s[4] = yf; s[5] = yt;
    }
    // ---- row r1: gx = D1-S1, gy = H-S1, gz = shift(S1) ----
    {
      float xd = 0, xf = 0, xt = 0, yd = 0, yf = 0, yt = 0;
#pragma unroll
      for (int j = 0; j < 4; ++j) {
        const float f0 = ELEM(S1f, j), t0 = ELEM(S1t, j);
        const float gxf = ELEM(D1f, j) - f0, gxt = ELEM(D1t, j) - t0;
        const float gyf = ELEM(Hf, j) - f0, gyt = ELEM(Ht, j) - t0;
        const float fnx = (j < 3) ? ELEM(S1f, j + 1) : s1fz;
        const float tnx = (j < 3) ? ELEM(S1t, j + 1) : s1tz;
        const float gzf = fnx - f0, gzt = tnx - t0;
        xd += gxf * gxt; xf += gxf * gxf; xt += gxt * gxt;
        yd += gyf * gyt; yf += gyf * gyf; yt += gyt * gyt;
        aH[j * 6 + 0] += gxf * gxt; aH[j * 6 + 1] += gxf * gxf; aH[j * 6 + 2] += gxt * gxt;
        aH[j * 6 + 3] += gzf * gzt; aH[j * 6 + 4] += gzf * gzf; aH[j * 6 + 5] += gzt * gzt;
        aD[(4 + j) * 6 + 0] += gyf * gyt; aD[(4 + j) * 6 + 1] += gyf * gyf; aD[(4 + j) * 6 + 2] += gyt * gyt;
        aD[(4 + j) * 6 + 3] += gzf * gzt; aD[(4 + j) * 6 + 4] += gzf * gzf; aD[(4 + j) * 6 + 5] += gzt * gzt;
      }
      float* s = &sw[((g * 2 + 1) * 40 + l) * 7];
      s[0] = xd; s[1] = xf; s[2] = xt; s[3] = yd; s[4] = yf; s[5] = yt;
    }
    // dump alongH partials
    {
      float* s2 = &sh[(g * 40 + l) * 25];
#pragma unroll
      for (int c = 0; c < 24; ++c) s2[c] = aH[c];
    }
    // register chain: next selves = this phase's d-neighbors; D <- prefetched
    S0f = D0f; S0t = D0t; S1f = D1f; S1t = D1t;
    s0fz = d0fz; s0tz = d0tz; s1fz = d1fz; s1tz = d1tz;
    if (p < Dt - 1) {
      D0f = nD0f; D0t = nD0t; D1f = nD1f; D1t = nD1t;
      d0fz = n0fz; d0tz = n0tz; d1fz = n1fz; d1tz = n1tz;
    }
    __syncthreads();

    if (tid < 240) {
      // alongH reduce over 8 groups + coalesced f4 write to pH
      const int cc = tid / 40, ll = tid % 40;
      float v0 = 0, v1 = 0, v2 = 0, v3 = 0;
#pragma unroll
      for (int gg = 0; gg < 8; ++gg) {
        const float* q = &sh[(gg * 40 + ll) * 25];
        v0 += q[0 * 6 + cc]; v1 += q[1 * 6 + cc]; v2 += q[2 * 6 + cc]; v3 += q[3 * 6 + cc];
      }
      const int bd = b * DD + d;
      float4 o; o.x = v0; o.y = v1; o.z = v2; o.w = v3;
      *(float4*)(pH + ((size_t)(hc * 6 + cc)) * NV + bd * 160 + 4 * ll) = o;
    } else {
      // alongW reduce over 40 lanes: 96 tasks on 80 threads
      for (int k = tid - 240; k < HCS * 6; k += 80) {
        const int row = k / 6, c = k % 6;
        float s = 0.0f;
#pragma unroll 8
        for (int ll = 0; ll < 40; ++ll) s += sw[(row * 40 + ll) * 7 + c];
        red[row][c] = s;
      }
    }
    __syncthreads();
    if (tid < HCS) {
      const float cx = red[tid][0] / (fmaxf(sqrtf(red[tid][1]), EPS) * fmaxf(sqrtf(red[tid][2]), EPS));
      const float cy = red[tid][3] / (fmaxf(sqrtf(red[tid][4]), EPS) * fmaxf(sqrtf(red[tid][5]), EPS));
      accCos += cx + cy;
    }
  }

  // ---- alongD: 48 atomic dword adds into the 1.23 MB cache-resident pD2 ----
#pragma unroll
  for (int r = 0; r < 2; ++r) {
    const int h = r0 + r;
#pragma unroll
    for (int cc = 0; cc < 6; ++cc) {
      float* base = pD2 + (size_t)cc * NV + b * SLICE + h * 160 + 4 * l;
#pragma unroll
      for (int j = 0; j < 4; ++j)
        atomicAdd(base + j, aD[(r * 4 + j) * 6 + cc]);
    }
  }

  if (tid < HCS) cpad[tid] = accCos;
  __syncthreads();
  if (tid == 0) {
    float s = 0.0f;
#pragma unroll
    for (int i = 0; i < HCS; ++i) s += cpad[i];
    atomicAdd(out, s * SCALE);
  }
}

// ---------------------------------------------------------------------------
// Combine partials -> cosines -> loss.
// types: 0 gx-alongH, 1 gz-alongH (sum 10 hc from PH);
//        2 gy-alongD, 3 gz-alongD (already-final sums in PD2, direct read).
// ---------------------------------------------------------------------------
__global__ __launch_bounds__(256) void finalize_kernel(const float* __restrict__ PH,
                                                       const float* __restrict__ PD2,
                                                       float* __restrict__ out) {
  const int v = blockIdx.x * 256 + threadIdx.x;
  float c = 0.0f;
  if (v < 4 * NV) {
    const int type = v / NV;
    const int vec = v % NV;
    float dot = 0.0f, ff = 0.0f, tt = 0.0f;
    if (type < 2) {
      const float* base = PH + (size_t)(type * 3) * NV + vec;
#pragma unroll
      for (int ch = 0; ch < NHC; ++ch) {
        const float* q = base + (size_t)(ch * 6) * NV;
        dot += q[0]; ff += q[(size_t)NV]; tt += q[2 * (size_t)NV];
      }
    } else {
      const float* q = PD2 + (size_t)((type - 2) * 3) * NV + vec;
      dot = q[0]; ff = q[(size_t)NV]; tt = q[2 * (size_t)NV];
    }
    c = dot / (fmaxf(sqrtf(ff), EPS) * fmaxf(sqrtf(tt), EPS));
  }
#pragma unroll
  for (int m = 32; m >= 1; m >>= 1) c += __shfl_xor(c, m);
  __shared__ float part[4];
  if ((threadIdx.x & 63) == 0) part[threadIdx.x >> 6] = c;
  __syncthreads();
  if (threadIdx.x == 0) atomicAdd(out, (part[0] + part[1] + part[2] + part[3]) * SCALE);
}

extern "C" void kernel_launch(void* const* d_in, const int* in_sizes, int n_in,
                              void* d_out, int out_size, void* d_ws, size_t ws_size,
                              hipStream_t stream) {
  const float* fk = (const float*)d_in[0];
  const float* tr = (const float*)d_in[1];
  float* out = (float*)d_out;
  float* PH  = (float*)d_ws;                        // [NHC][6][NV] = 12.3 MB
  float* PD2 = PH + (size_t)NHC * 6 * NV;           // [6][NV]      =  1.23 MB

  hipLaunchKernelGGL(zeroP, dim3(6 * NV / 4 / 256), dim3(256), 0, stream,
                     (float4*)PD2, out);
  hipLaunchKernelGGL(mainS2, dim3(NB * NDC * NHC), dim3(NTHR), 0, stream,
                     fk, tr, PH, PD2, out);
  hipLaunchKernelGGL(finalize_kernel, dim3((4 * NV + 255) / 256), dim3(256), 0, stream,
                     PH, PD2, out);
}

// Round 5
// 206.646 us; speedup vs baseline: 1.4203x; 1.4203x over previous
//
#include <hip/hip_runtime.h>
#include <math.h>

#define DD 160
#define HH 160
#define WW 160
#define NB 2
#define SLICE (HH * WW)        // 25600
#define NV 51200               // NB*160*160 vectors per reduction type
#define Dt 8                   // d's per block-chunk
#define NDC 20                 // d-chunks (160/Dt)
#define NHC 10                 // h-chunks
#define HCS 16                 // rows per h-chunk
#define NTHR 320               // 8 groups x 40 float4-lanes
#define NBLK (NB * NDC * NHC)  // 400 blocks

static constexpr float EPS = 1e-12f;
static constexpr float SCALE = -1.0f / 960.0f;  // -(six cos sums)/(160*2*3)

#define ELEM(v, j) ((j) == 0 ? (v).x : ((j) == 1 ? (v).y : ((j) == 2 ? (v).z : (v).w)))

// ---------------------------------------------------------------------------
// mainY (launch 1 of 2): per-(b,dc,hc) chunk over 8 d-phases.
//  - alongW cosines completed in-block -> deterministic cosB[bid] store.
//  - alongH partials -> pH[10][6][NV] (LDS-combined over 8 groups).
//  - alongD partials in 48 persistent VGPRs -> f4 dump to pD[20][6][NV]
//    (24.6 MB, half of round-0's spill; round-3 showed fp32 atomics cost
//    242 MB of RMW traffic, round-4 showed grid.sync races in this harness,
//    so cross-block combining happens at the kernel boundary only).
//  - block 0 zeroes out[0] (finalize's atomics run in the next dispatch).
// ---------------------------------------------------------------------------
__global__ __launch_bounds__(NTHR, 2) void mainY(const float* __restrict__ f,
                                                 const float* __restrict__ t,
                                                 float* __restrict__ pH,
                                                 float* __restrict__ pD,
                                                 float* __restrict__ cosB,
                                                 float* __restrict__ out) {
  __shared__ float sw[HCS * 40 * 7];    // per-(row,lane) alongW partials
  __shared__ float sh[8 * 40 * 25];     // per-(group,lane) alongH partials
  __shared__ float red[HCS][6];
  __shared__ float cpad[HCS];
  const int tid = threadIdx.x;
  const int g = tid / 40;               // group 0..7
  const int l = tid % 40;               // float4-lane
  const int w = 4 * l;
  const int wn = (w + 4 < WW) ? (w + 4) : (WW - 1);  // clamp -> gz[3]=0 at w=159
  const int bid = blockIdx.x;
  const int hc = bid % NHC;
  const int t2 = bid / NHC;
  const int dc = t2 % NDC;
  const int b  = t2 / NDC;
  const int d0 = dc * Dt;
  const int r0 = hc * HCS + g * 2;      // thread's two consecutive rows
  const int r1 = r0 + 1;
  const int r2 = (r1 + 1 < HH) ? (r1 + 1) : (HH - 1);  // clamp -> gy=0 at h=159
  const float* fb = f + (size_t)b * DD * SLICE;
  const float* tb = t + (size_t)b * DD * SLICE;

  if (bid == 0 && tid == 0) out[0] = 0.0f;

  // chain selves: slice d0, rows r0,r1 (+ wn scalars)
  float4 S0f = *(const float4*)(fb + (size_t)d0 * SLICE + r0 * WW + w);
  float4 S0t = *(const float4*)(tb + (size_t)d0 * SLICE + r0 * WW + w);
  float4 S1f = *(const float4*)(fb + (size_t)d0 * SLICE + r1 * WW + w);
  float4 S1t = *(const float4*)(tb + (size_t)d0 * SLICE + r1 * WW + w);
  float s0fz = (fb + (size_t)d0 * SLICE + r0 * WW)[wn];
  float s0tz = (tb + (size_t)d0 * SLICE + r0 * WW)[wn];
  float s1fz = (fb + (size_t)d0 * SLICE + r1 * WW)[wn];
  float s1tz = (tb + (size_t)d0 * SLICE + r1 * WW)[wn];
  // prefetched d-neighbor slice d0+1 (d0 <= 152, always in range)
  const float* fN0 = fb + (size_t)(d0 + 1) * SLICE;
  const float* tN0 = tb + (size_t)(d0 + 1) * SLICE;
  float4 D0f = *(const float4*)(fN0 + r0 * WW + w);
  float4 D0t = *(const float4*)(tN0 + r0 * WW + w);
  float4 D1f = *(const float4*)(fN0 + r1 * WW + w);
  float4 D1t = *(const float4*)(tN0 + r1 * WW + w);
  float d0fz = (fN0 + r0 * WW)[wn], d0tz = (tN0 + r0 * WW)[wn];
  float d1fz = (fN0 + r1 * WW)[wn], d1tz = (tN0 + r1 * WW)[wn];

  float aD[48];                         // alongD (gy,gz) persistent accumulators
#pragma unroll
  for (int c = 0; c < 48; ++c) aD[c] = 0.0f;
  float accCos = 0.0f;

#pragma unroll
  for (int p = 0; p < Dt; ++p) {
    const int d = d0 + p;
    const float* fS = fb + (size_t)d * SLICE;
    const float* tS = tb + (size_t)d * SLICE;
    // same-slice row r2 (L1/L2 hit: neighbor group loaded it last phase)
    const float4 Hf = *(const float4*)(fS + r2 * WW + w);
    const float4 Ht = *(const float4*)(tS + r2 * WW + w);
    // prefetch NEXT phase's d-neighbor slice (the cold loads)
    float4 nD0f = {0, 0, 0, 0}, nD0t = {0, 0, 0, 0};
    float4 nD1f = {0, 0, 0, 0}, nD1t = {0, 0, 0, 0};
    float n0fz = 0.f, n0tz = 0.f, n1fz = 0.f, n1tz = 0.f;
    if (p < Dt - 1) {
      const int nd = d + 1;
      const int ndn = (nd + 1 < DD) ? (nd + 1) : nd;  // clamp -> gx=0 at d=159
      const float* fN = fb + (size_t)ndn * SLICE;
      const float* tN = tb + (size_t)ndn * SLICE;
      nD0f = *(const float4*)(fN + r0 * WW + w);
      nD0t = *(const float4*)(tN + r0 * WW + w);
      nD1f = *(const float4*)(fN + r1 * WW + w);
      nD1t = *(const float4*)(tN + r1 * WW + w);
      n0fz = (fN + r0 * WW)[wn]; n0tz = (tN + r0 * WW)[wn];
      n1fz = (fN + r1 * WW)[wn]; n1tz = (tN + r1 * WW)[wn];
    }

    float aH[24];
#pragma unroll
    for (int c = 0; c < 24; ++c) aH[c] = 0.0f;

    // ---- row r0: gx = D0-S0, gy = S1-S0, gz = shift(S0) ----
    {
      float xd = 0, xf = 0, xt = 0, yd = 0, yf = 0, yt = 0;
#pragma unroll
      for (int j = 0; j < 4; ++j) {
        const float f0 = ELEM(S0f, j), t0 = ELEM(S0t, j);
        const float gxf = ELEM(D0f, j) - f0, gxt = ELEM(D0t, j) - t0;
        const float gyf = ELEM(S1f, j) - f0, gyt = ELEM(S1t, j) - t0;
        const float fnx = (j < 3) ? ELEM(S0f, j + 1) : s0fz;
        const float tnx = (j < 3) ? ELEM(S0t, j + 1) : s0tz;
        const float gzf = fnx - f0, gzt = tnx - t0;
        xd += gxf * gxt; xf += gxf * gxf; xt += gxt * gxt;
        yd += gyf * gyt; yf += gyf * gyf; yt += gyt * gyt;
        aH[j * 6 + 0] += gxf * gxt; aH[j * 6 + 1] += gxf * gxf; aH[j * 6 + 2] += gxt * gxt;
        aH[j * 6 + 3] += gzf * gzt; aH[j * 6 + 4] += gzf * gzf; aH[j * 6 + 5] += gzt * gzt;
        aD[j * 6 + 0] += gyf * gyt; aD[j * 6 + 1] += gyf * gyf; aD[j * 6 + 2] += gyt * gyt;
        aD[j * 6 + 3] += gzf * gzt; aD[j * 6 + 4] += gzf * gzf; aD[j * 6 + 5] += gzt * gzt;
      }
      float* s = &sw[((g * 2 + 0) * 40 + l) * 7];
      s[0] = xd; s[1] = xf; s[2] = xt; s[3] = yd; s[4] = yf; s[5] = yt;
    }
    // ---- row r1: gx = D1-S1, gy = H-S1, gz = shift(S1) ----
    {
      float xd = 0, xf = 0, xt = 0, yd = 0, yf = 0, yt = 0;
#pragma unroll
      for (int j = 0; j < 4; ++j) {
        const float f0 = ELEM(S1f, j), t0 = ELEM(S1t, j);
        const float gxf = ELEM(D1f, j) - f0, gxt = ELEM(D1t, j) - t0;
        const float gyf = ELEM(Hf, j) - f0, gyt = ELEM(Ht, j) - t0;
        const float fnx = (j < 3) ? ELEM(S1f, j + 1) : s1fz;
        const float tnx = (j < 3) ? ELEM(S1t, j + 1) : s1tz;
        const float gzf = fnx - f0, gzt = tnx - t0;
        xd += gxf * gxt; xf += gxf * gxf; xt += gxt * gxt;
        yd += gyf * gyt; yf += gyf * gyf; yt += gyt * gyt;
        aH[j * 6 + 0] += gxf * gxt; aH[j * 6 + 1] += gxf * gxf; aH[j * 6 + 2] += gxt * gxt;
        aH[j * 6 + 3] += gzf * gzt; aH[j * 6 + 4] += gzf * gzf; aH[j * 6 + 5] += gzt * gzt;
        aD[(4 + j) * 6 + 0] += gyf * gyt; aD[(4 + j) * 6 + 1] += gyf * gyf; aD[(4 + j) * 6 + 2] += gyt * gyt;
        aD[(4 + j) * 6 + 3] += gzf * gzt; aD[(4 + j) * 6 + 4] += gzf * gzf; aD[(4 + j) * 6 + 5] += gzt * gzt;
      }
      float* s = &sw[((g * 2 + 1) * 40 + l) * 7];
      s[0] = xd; s[1] = xf; s[2] = xt; s[3] = yd; s[4] = yf; s[5] = yt;
    }
    // dump alongH partials
    {
      float* s2 = &sh[(g * 40 + l) * 25];
#pragma unroll
      for (int c = 0; c < 24; ++c) s2[c] = aH[c];
    }
    // register chain: next selves = this phase's d-neighbors; D <- prefetched
    S0f = D0f; S0t = D0t; S1f = D1f; S1t = D1t;
    s0fz = d0fz; s0tz = d0tz; s1fz = d1fz; s1tz = d1tz;
    if (p < Dt - 1) {
      D0f = nD0f; D0t = nD0t; D1f = nD1f; D1t = nD1t;
      d0fz = n0fz; d0tz = n0tz; d1fz = n1fz; d1tz = n1tz;
    }
    __syncthreads();

    if (tid < 240) {
      // alongH reduce over 8 groups + coalesced f4 write to pH
      const int cc = tid / 40, ll = tid % 40;
      float v0 = 0, v1 = 0, v2 = 0, v3 = 0;
#pragma unroll
      for (int gg = 0; gg < 8; ++gg) {
        const float* q = &sh[(gg * 40 + ll) * 25];
        v0 += q[0 * 6 + cc]; v1 += q[1 * 6 + cc]; v2 += q[2 * 6 + cc]; v3 += q[3 * 6 + cc];
      }
      const int bd = b * DD + d;
      float4 o; o.x = v0; o.y = v1; o.z = v2; o.w = v3;
      *(float4*)(pH + ((size_t)(hc * 6 + cc)) * NV + bd * 160 + 4 * ll) = o;
    } else {
      // alongW reduce over 40 lanes: 96 tasks on 80 threads
      for (int k = tid - 240; k < HCS * 6; k += 80) {
        const int row = k / 6, c = k % 6;
        float s = 0.0f;
#pragma unroll 8
        for (int ll = 0; ll < 40; ++ll) s += sw[(row * 40 + ll) * 7 + c];
        red[row][c] = s;
      }
    }
    __syncthreads();
    if (tid < HCS) {
      const float cx = red[tid][0] / (fmaxf(sqrtf(red[tid][1]), EPS) * fmaxf(sqrtf(red[tid][2]), EPS));
      const float cy = red[tid][3] / (fmaxf(sqrtf(red[tid][4]), EPS) * fmaxf(sqrtf(red[tid][5]), EPS));
      accCos += cx + cy;
    }
  }

  // ---- alongD chunk partials: 12 coalesced f4 stores per thread ----
#pragma unroll
  for (int r = 0; r < 2; ++r) {
    const int h = r0 + r;
#pragma unroll
    for (int cc = 0; cc < 6; ++cc) {
      float4 o;
      o.x = aD[(r * 4 + 0) * 6 + cc];
      o.y = aD[(r * 4 + 1) * 6 + cc];
      o.z = aD[(r * 4 + 2) * 6 + cc];
      o.w = aD[(r * 4 + 3) * 6 + cc];
      *(float4*)(pD + ((size_t)(dc * 6 + cc)) * NV + b * SLICE + h * 160 + 4 * l) = o;
    }
  }

  // ---- deterministic alongW export ----
  if (tid < HCS) cpad[tid] = accCos;
  __syncthreads();
  if (tid == 0) {
    float s = 0.0f;
#pragma unroll
    for (int i = 0; i < HCS; ++i) s += cpad[i];
    cosB[bid] = s;
  }
}

// ---------------------------------------------------------------------------
// finalizeY (launch 2 of 2): combine chunk partials -> cosines -> loss.
// types: 0 gx-alongH, 1 gz-alongH (sum 10 hc); 2 gy-alongD, 3 gz-alongD
// (sum 20 dc). Block 0 additionally folds the 400 alongW block-cosines.
// 800 atomicAdds on out total (out zeroed by mainY in the prior dispatch).
// ---------------------------------------------------------------------------
__global__ __launch_bounds__(256) void finalizeY(const float* __restrict__ PH,
                                                 const float* __restrict__ PD,
                                                 const float* __restrict__ cosB,
                                                 float* __restrict__ out) {
  const int v = blockIdx.x * 256 + threadIdx.x;
  float c = 0.0f;
  if (v < 4 * NV) {
    const int type = v / NV;
    const int vec = v % NV;
    float dot = 0.0f, ff = 0.0f, tt = 0.0f;
    if (type < 2) {
      const float* base = PH + (size_t)(type * 3) * NV + vec;
#pragma unroll
      for (int ch = 0; ch < NHC; ++ch) {
        const float* q = base + (size_t)(ch * 6) * NV;
        dot += q[0]; ff += q[(size_t)NV]; tt += q[2 * (size_t)NV];
      }
    } else {
      const float* base = PD + (size_t)((type - 2) * 3) * NV + vec;
#pragma unroll
      for (int ch = 0; ch < NDC; ++ch) {
        const float* q = base + (size_t)(ch * 6) * NV;
        dot += q[0]; ff += q[(size_t)NV]; tt += q[2 * (size_t)NV];
      }
    }
    c = dot / (fmaxf(sqrtf(ff), EPS) * fmaxf(sqrtf(tt), EPS));
  }
  if (blockIdx.x == 0) {
    c += cosB[threadIdx.x];
    if (threadIdx.x < NBLK - 256) c += cosB[threadIdx.x + 256];
  }
#pragma unroll
  for (int m = 32; m >= 1; m >>= 1) c += __shfl_xor(c, m);
  __shared__ float part[4];
  if ((threadIdx.x & 63) == 0) part[threadIdx.x >> 6] = c;
  __syncthreads();
  if (threadIdx.x == 0) atomicAdd(out, (part[0] + part[1] + part[2] + part[3]) * SCALE);
}

extern "C" void kernel_launch(void* const* d_in, const int* in_sizes, int n_in,
                              void* d_out, int out_size, void* d_ws, size_t ws_size,
                              hipStream_t stream) {
  const float* fk = (const float*)d_in[0];
  const float* tr = (const float*)d_in[1];
  float* outp = (float*)d_out;
  float* PH = (float*)d_ws;                         // [NHC][6][NV] = 12.3 MB
  float* PD = PH + (size_t)NHC * 6 * NV;            // [NDC][6][NV] = 24.6 MB
  float* CB = PD + (size_t)NDC * 6 * NV;            // [NBLK] alongW block partials

  hipLaunchKernelGGL(mainY, dim3(NBLK), dim3(NTHR), 0, stream,
                     fk, tr, PH, PD, CB, outp);
  hipLaunchKernelGGL(finalizeY, dim3((4 * NV + 255) / 256), dim3(256), 0, stream,
                     PH, PD, CB, outp);
}

// Round 7
// 141.055 us; speedup vs baseline: 2.0807x; 1.4650x over previous
//
#include <hip/hip_runtime.h>
#include <math.h>

#define DD 160
#define HH 160
#define WW 160
#define NB 2
#define SLICE (HH * WW)        // 25600
#define NV 51200               // NB*160*160 vectors per reduction type
#define Dt 4                   // d's per block (R0-proven: no spill at 128 VGPR)
#define NDC 40                 // d-chunks (160/Dt)
#define NHC 10                 // h-chunks
#define HCS 16                 // rows per h-chunk
#define NTHR 320               // 8 groups x 40 float4-lanes
#define NBLK (NB * NDC * NHC)  // 800 blocks (3 blocks/CU resident -> good TLP)

static constexpr float EPS = 1e-12f;
static constexpr float SCALE = -1.0f / 960.0f;  // -(six cos sums)/(160*2*3)

#define ELEM(v, j) ((j) == 0 ? (v).x : ((j) == 1 ? (v).y : ((j) == 2 ? (v).z : (v).w)))

__global__ void zero_kernel(float* out) {
  if (threadIdx.x == 0) out[0] = 0.0f;
}

// ---------------------------------------------------------------------------
// mainS: EXACT round-0 body (verified 56.6us, spill-free, absmax 0.0).
// Workspace is exactly 300*NV floats = round-0's proven allocation; round-6's
// extra cosB array (3.2KB past 300*NV) was a possible OOB -> removed, alongW
// block cosines go back to one atomicAdd per block (R0 mechanism, 800 total).
// ---------------------------------------------------------------------------
__global__ __launch_bounds__(NTHR, 2) void mainS(const float* __restrict__ f,
                                                 const float* __restrict__ t,
                                                 float* __restrict__ P,
                                                 float* __restrict__ out) {
  __shared__ float sw[HCS * 40 * 7];    // per-(row,lane) alongW partials
  __shared__ float sh[8 * 40 * 25];     // per-(group,lane) alongH partials
  __shared__ float red[HCS][6];
  __shared__ float cpad[HCS];
  const int tid = threadIdx.x;
  const int g = tid / 40;               // group 0..7
  const int l = tid % 40;               // float4-lane
  const int w = 4 * l;
  const int wn = (w + 4 < WW) ? (w + 4) : (WW - 1);  // clamp -> gz[3]=0 at w=159
  const int hc = blockIdx.x % NHC;
  const int t2 = blockIdx.x / NHC;
  const int dc = t2 % NDC;
  const int b  = t2 / NDC;
  const int d0 = dc * Dt;
  const int r0 = hc * HCS + g * 2;      // thread's two consecutive rows
  const int r1 = r0 + 1;
  const int r2 = (r1 + 1 < HH) ? (r1 + 1) : (HH - 1);  // clamp -> gy=0 at h=159
  const float* fb = f + (size_t)b * DD * SLICE;
  const float* tb = t + (size_t)b * DD * SLICE;
  float* pH = P;                                  // [NHC][6][NV], vec=(b,d,w)
  float* pD = P + (size_t)NHC * 6 * NV;           // [NDC][6][NV], vec=(b,h,w)

  // init chained self: slice d0, rows r0,r1 (+ wn scalars)
  float4 S0f = *(const float4*)(fb + (size_t)d0 * SLICE + r0 * WW + w);
  float4 S0t = *(const float4*)(tb + (size_t)d0 * SLICE + r0 * WW + w);
  float4 S1f = *(const float4*)(fb + (size_t)d0 * SLICE + r1 * WW + w);
  float4 S1t = *(const float4*)(tb + (size_t)d0 * SLICE + r1 * WW + w);
  float s0fz = (fb + (size_t)d0 * SLICE + r0 * WW)[wn];
  float s0tz = (tb + (size_t)d0 * SLICE + r0 * WW)[wn];
  float s1fz = (fb + (size_t)d0 * SLICE + r1 * WW)[wn];
  float s1tz = (tb + (size_t)d0 * SLICE + r1 * WW)[wn];

  float aD[48];                         // alongD (gy,gz) persistent accumulators
#pragma unroll
  for (int c = 0; c < 48; ++c) aD[c] = 0.0f;
  float accCos = 0.0f;

#pragma unroll
  for (int p = 0; p < Dt; ++p) {
    const int d = d0 + p;
    const int dn = (d + 1 < DD) ? (d + 1) : d;  // clamp -> gx = 0 at d=159
    const float* fS = fb + (size_t)d * SLICE;
    const float* tS = tb + (size_t)d * SLICE;
    const float* fN = fb + (size_t)dn * SLICE;
    const float* tN = tb + (size_t)dn * SLICE;
    // per-phase loads: 6 f4 + 4 scalars, all independent
    const float4 Hf  = *(const float4*)(fS + r2 * WW + w);   // row r2 self (gy for r1)
    const float4 Ht  = *(const float4*)(tS + r2 * WW + w);
    const float4 D0f = *(const float4*)(fN + r0 * WW + w);   // next-d self r0
    const float4 D0t = *(const float4*)(tN + r0 * WW + w);
    const float4 D1f = *(const float4*)(fN + r1 * WW + w);   // next-d self r1
    const float4 D1t = *(const float4*)(tN + r1 * WW + w);
    const float d0fz = (fN + r0 * WW)[wn], d0tz = (tN + r0 * WW)[wn];
    const float d1fz = (fN + r1 * WW)[wn], d1tz = (tN + r1 * WW)[wn];

    float aH[24];
#pragma unroll
    for (int c = 0; c < 24; ++c) aH[c] = 0.0f;

    // ---- row r0: gx = D0-S0, gy = S1-S0, gz = shift(S0) ----
    {
      float xd = 0, xf = 0, xt = 0, yd = 0, yf = 0, yt = 0;
#pragma unroll
      for (int j = 0; j < 4; ++j) {
        const float f0 = ELEM(S0f, j), t0 = ELEM(S0t, j);
        const float gxf = ELEM(D0f, j) - f0, gxt = ELEM(D0t, j) - t0;
        const float gyf = ELEM(S1f, j) - f0, gyt = ELEM(S1t, j) - t0;
        const float fnx = (j < 3) ? ELEM(S0f, j + 1) : s0fz;
        const float tnx = (j < 3) ? ELEM(S0t, j + 1) : s0tz;
        const float gzf = fnx - f0, gzt = tnx - t0;
        xd += gxf * gxt; xf += gxf * gxf; xt += gxt * gxt;
        yd += gyf * gyt; yf += gyf * gyf; yt += gyt * gyt;
        aH[j * 6 + 0] += gxf * gxt; aH[j * 6 + 1] += gxf * gxf; aH[j * 6 + 2] += gxt * gxt;
        aH[j * 6 + 3] += gzf * gzt; aH[j * 6 + 4] += gzf * gzf; aH[j * 6 + 5] += gzt * gzt;
        aD[j * 6 + 0] += gyf * gyt; aD[j * 6 + 1] += gyf * gyf; aD[j * 6 + 2] += gyt * gyt;
        aD[j * 6 + 3] += gzf * gzt; aD[j * 6 + 4] += gzf * gzf; aD[j * 6 + 5] += gzt * gzt;
      }
      float* s = &sw[((g * 2 + 0) * 40 + l) * 7];
      s[0] = xd; s[1] = xf; s[2] = xt; s[3] = yd; s[4] = yf; s[5] = yt;
    }
    // ---- row r1: gx = D1-S1, gy = H-S1, gz = shift(S1) ----
    {
      float xd = 0, xf = 0, xt = 0, yd = 0, yf = 0, yt = 0;
#pragma unroll
      for (int j = 0; j < 4; ++j) {
        const float f0 = ELEM(S1f, j), t0 = ELEM(S1t, j);
        const float gxf = ELEM(D1f, j) - f0, gxt = ELEM(D1t, j) - t0;
        const float gyf = ELEM(Hf, j) - f0, gyt = ELEM(Ht, j) - t0;
        const float fnx = (j < 3) ? ELEM(S1f, j + 1) : s1fz;
        const float tnx = (j < 3) ? ELEM(S1t, j + 1) : s1tz;
        const float gzf = fnx - f0, gzt = tnx - t0;
        xd += gxf * gxt; xf += gxf * gxf; xt += gxt * gxt;
        yd += gyf * gyt; yf += gyf * gyf; yt += gyt * gyt;
        aH[j * 6 + 0] += gxf * gxt; aH[j * 6 + 1] += gxf * gxf; aH[j * 6 + 2] += gxt * gxt;
        aH[j * 6 + 3] += gzf * gzt; aH[j * 6 + 4] += gzf * gzf; aH[j * 6 + 5] += gzt * gzt;
        aD[(4 + j) * 6 + 0] += gyf * gyt; aD[(4 + j) * 6 + 1] += gyf * gyf; aD[(4 + j) * 6 + 2] += gyt * gyt;
        aD[(4 + j) * 6 + 3] += gzf * gzt; aD[(4 + j) * 6 + 4] += gzf * gzf; aD[(4 + j) * 6 + 5] += gzt * gzt;
      }
      float* s = &sw[((g * 2 + 1) * 40 + l) * 7];
      s[0] = xd; s[1] = xf; s[2] = xt; s[3] = yd; s[4] = yf; s[5] = yt;
    }
    // dump alongH partials
    {
      float* s2 = &sh[(g * 40 + l) * 25];
#pragma unroll
      for (int c = 0; c < 24; ++c) s2[c] = aH[c];
    }
    // register chain: next phase's selves are this phase's d-neighbors
    S0f = D0f; S0t = D0t; S1f = D1f; S1t = D1t;
    s0fz = d0fz; s0tz = d0tz; s1fz = d1fz; s1tz = d1tz;
    __syncthreads();

    if (tid < 240) {
      // alongH reduce over 8 groups + coalesced f4 write to pH
      const int cc = tid / 40, ll = tid % 40;
      float v0 = 0, v1 = 0, v2 = 0, v3 = 0;
#pragma unroll
      for (int gg = 0; gg < 8; ++gg) {
        const float* q = &sh[(gg * 40 + ll) * 25];
        v0 += q[0 * 6 + cc]; v1 += q[1 * 6 + cc]; v2 += q[2 * 6 + cc]; v3 += q[3 * 6 + cc];
      }
      const int bd = b * DD + d;
      float4 o; o.x = v0; o.y = v1; o.z = v2; o.w = v3;
      *(float4*)(pH + ((size_t)(hc * 6 + cc)) * NV + bd * 160 + 4 * ll) = o;
    } else {
      // alongW reduce over 40 lanes: 96 tasks on 80 threads
      for (int k = tid - 240; k < HCS * 6; k += 80) {
        const int row = k / 6, c = k % 6;
        float s = 0.0f;
#pragma unroll 8
        for (int ll = 0; ll < 40; ++ll) s += sw[(row * 40 + ll) * 7 + c];
        red[row][c] = s;
      }
    }
    __syncthreads();
    if (tid < HCS) {
      const float cx = red[tid][0] / (fmaxf(sqrtf(red[tid][1]), EPS) * fmaxf(sqrtf(red[tid][2]), EPS));
      const float cy = red[tid][3] / (fmaxf(sqrtf(red[tid][4]), EPS) * fmaxf(sqrtf(red[tid][5]), EPS));
      accCos += cx + cy;
    }
  }

  // ---- alongD partials: 12 coalesced f4 writes per thread ----
#pragma unroll
  for (int r = 0; r < 2; ++r) {
    const int h = r0 + r;
#pragma unroll
    for (int cc = 0; cc < 6; ++cc) {
      float4 o;
      o.x = aD[(r * 4 + 0) * 6 + cc];
      o.y = aD[(r * 4 + 1) * 6 + cc];
      o.z = aD[(r * 4 + 2) * 6 + cc];
      o.w = aD[(r * 4 + 3) * 6 + cc];
      *(float4*)(pD + ((size_t)(dc * 6 + cc)) * NV + b * SLICE + h * 160 + 4 * l) = o;
    }
  }

  if (tid < HCS) cpad[tid] = accCos;
  __syncthreads();
  if (tid == 0) {
    float s = 0.0f;
#pragma unroll
    for (int i = 0; i < HCS; ++i) s += cpad[i];
    atomicAdd(out, s * SCALE);
  }
}

// ---------------------------------------------------------------------------
// finalizeZ: float4-vectorized combine (round-6's new idea, hazard removed).
// Each thread computes 4 consecutive cosines of one type; all chunk streams
// are f4-contiguous in the [chunk][6][NV] layout. 51200 threads = 200 blocks
// (vs 204800 scalar threads with divergent type branches before).
// types: 0 gx-alongH, 1 gz-alongH (sum 10 hc); 2 gy-alongD, 3 gz-alongD (40 dc).
// ---------------------------------------------------------------------------
__global__ __launch_bounds__(256) void finalizeZ(const float* __restrict__ P,
                                                 float* __restrict__ out) {
  const float* PH = P;
  const float* PD = P + (size_t)NHC * 6 * NV;
  const int v4 = blockIdx.x * 256 + threadIdx.x;   // 0 .. 4*NV/4-1, exact grid
  const int type = v4 / (NV / 4);
  const int vec4 = (v4 % (NV / 4)) * 4;
  float4 dot = {0, 0, 0, 0}, ff = {0, 0, 0, 0}, tt = {0, 0, 0, 0};
  if (type < 2) {
    const float* base = PH + (size_t)(type * 3) * NV + vec4;
#pragma unroll
    for (int ch = 0; ch < NHC; ++ch) {
      const float* q = base + (size_t)(ch * 6) * NV;
      const float4 a  = *(const float4*)(q);
      const float4 bb = *(const float4*)(q + (size_t)NV);
      const float4 cv = *(const float4*)(q + 2 * (size_t)NV);
      dot.x += a.x;  dot.y += a.y;  dot.z += a.z;  dot.w += a.w;
      ff.x += bb.x;  ff.y += bb.y;  ff.z += bb.z;  ff.w += bb.w;
      tt.x += cv.x;  tt.y += cv.y;  tt.z += cv.z;  tt.w += cv.w;
    }
  } else {
    const float* base = PD + (size_t)((type - 2) * 3) * NV + vec4;
#pragma unroll 8
    for (int ch = 0; ch < NDC; ++ch) {
      const float* q = base + (size_t)(ch * 6) * NV;
      const float4 a  = *(const float4*)(q);
      const float4 bb = *(const float4*)(q + (size_t)NV);
      const float4 cv = *(const float4*)(q + 2 * (size_t)NV);
      dot.x += a.x;  dot.y += a.y;  dot.z += a.z;  dot.w += a.w;
      ff.x += bb.x;  ff.y += bb.y;  ff.z += bb.z;  ff.w += bb.w;
      tt.x += cv.x;  tt.y += cv.y;  tt.z += cv.z;  tt.w += cv.w;
    }
  }
  float c = dot.x / (fmaxf(sqrtf(ff.x), EPS) * fmaxf(sqrtf(tt.x), EPS))
          + dot.y / (fmaxf(sqrtf(ff.y), EPS) * fmaxf(sqrtf(tt.y), EPS))
          + dot.z / (fmaxf(sqrtf(ff.z), EPS) * fmaxf(sqrtf(tt.z), EPS))
          + dot.w / (fmaxf(sqrtf(ff.w), EPS) * fmaxf(sqrtf(tt.w), EPS));
#pragma unroll
  for (int m = 32; m >= 1; m >>= 1) c += __shfl_xor(c, m);
  __shared__ float part[4];
  if ((threadIdx.x & 63) == 0) part[threadIdx.x >> 6] = c;
  __syncthreads();
  if (threadIdx.x == 0) atomicAdd(out, (part[0] + part[1] + part[2] + part[3]) * SCALE);
}

extern "C" void kernel_launch(void* const* d_in, const int* in_sizes, int n_in,
                              void* d_out, int out_size, void* d_ws, size_t ws_size,
                              hipStream_t stream) {
  const float* fk = (const float*)d_in[0];
  const float* tr = (const float*)d_in[1];
  float* outp = (float*)d_out;
  float* P = (float*)d_ws;   // (NHC+NDC)*6*NV floats = 61.44 MB (== round-0 size)

  hipLaunchKernelGGL(zero_kernel, dim3(1), dim3(64), 0, stream, outp);
  hipLaunchKernelGGL(mainS, dim3(NBLK), dim3(NTHR), 0, stream, fk, tr, P, outp);
  hipLaunchKernelGGL(finalizeZ, dim3(NV / 256), dim3(256), 0, stream, P, outp);
}

// Round 8
// 140.850 us; speedup vs baseline: 2.0837x; 1.0015x over previous
//
#include <hip/hip_runtime.h>
#include <math.h>

#define DD 160
#define HH 160
#define WW 160
#define NB 2
#define SLICE (HH * WW)        // 25600
#define NV 51200               // NB*160*160 vectors per reduction type
#define Dt 4                   // d's per block (R0-proven: no spill at 128 VGPR)
#define NDC 40                 // d-chunks (160/Dt)
#define NHC 10                 // h-chunks
#define HCS 16                 // rows per h-chunk
#define NTHR 320               // 8 groups x 40 float4-lanes
#define NBLK (NB * NDC * NHC)  // 800 blocks (3 blocks/CU resident -> good TLP)
#define NQ (NV / 4)            // 12800 f4-tasks per type

static constexpr float EPS = 1e-12f;
static constexpr float SCALE = -1.0f / 960.0f;  // -(six cos sums)/(160*2*3)

#define ELEM(v, j) ((j) == 0 ? (v).x : ((j) == 1 ? (v).y : ((j) == 2 ? (v).z : (v).w)))

__global__ void zero_kernel(float* out) {
  if (threadIdx.x == 0) out[0] = 0.0f;
}

// ---------------------------------------------------------------------------
// mainS: round-0 body (verified 56.6us, spill-free, absmax 0.0) with ONE
// change: the 12 f4 pD stores are hoisted into phase Dt-1 (before its first
// barrier) so the 49 MB write burst overlaps the final reduce instead of
// draining at kernel exit. Tripwire: WRITE_SIZE must stay 62.0 MB, VGPR 128.
// ---------------------------------------------------------------------------
__global__ __launch_bounds__(NTHR, 2) void mainS(const float* __restrict__ f,
                                                 const float* __restrict__ t,
                                                 float* __restrict__ P,
                                                 float* __restrict__ out) {
  __shared__ float sw[HCS * 40 * 7];    // per-(row,lane) alongW partials
  __shared__ float sh[8 * 40 * 25];     // per-(group,lane) alongH partials
  __shared__ float red[HCS][6];
  __shared__ float cpad[HCS];
  const int tid = threadIdx.x;
  const int g = tid / 40;               // group 0..7
  const int l = tid % 40;               // float4-lane
  const int w = 4 * l;
  const int wn = (w + 4 < WW) ? (w + 4) : (WW - 1);  // clamp -> gz[3]=0 at w=159
  const int hc = blockIdx.x % NHC;
  const int t2 = blockIdx.x / NHC;
  const int dc = t2 % NDC;
  const int b  = t2 / NDC;
  const int d0 = dc * Dt;
  const int r0 = hc * HCS + g * 2;      // thread's two consecutive rows
  const int r1 = r0 + 1;
  const int r2 = (r1 + 1 < HH) ? (r1 + 1) : (HH - 1);  // clamp -> gy=0 at h=159
  const float* fb = f + (size_t)b * DD * SLICE;
  const float* tb = t + (size_t)b * DD * SLICE;
  float* pH = P;                                  // [NHC][6][NV], vec=(b,d,w)
  float* pD = P + (size_t)NHC * 6 * NV;           // [NDC][6][NV], vec=(b,h,w)

  // init chained self: slice d0, rows r0,r1 (+ wn scalars)
  float4 S0f = *(const float4*)(fb + (size_t)d0 * SLICE + r0 * WW + w);
  float4 S0t = *(const float4*)(tb + (size_t)d0 * SLICE + r0 * WW + w);
  float4 S1f = *(const float4*)(fb + (size_t)d0 * SLICE + r1 * WW + w);
  float4 S1t = *(const float4*)(tb + (size_t)d0 * SLICE + r1 * WW + w);
  float s0fz = (fb + (size_t)d0 * SLICE + r0 * WW)[wn];
  float s0tz = (tb + (size_t)d0 * SLICE + r0 * WW)[wn];
  float s1fz = (fb + (size_t)d0 * SLICE + r1 * WW)[wn];
  float s1tz = (tb + (size_t)d0 * SLICE + r1 * WW)[wn];

  float aD[48];                         // alongD (gy,gz) persistent accumulators
#pragma unroll
  for (int c = 0; c < 48; ++c) aD[c] = 0.0f;
  float accCos = 0.0f;

#pragma unroll
  for (int p = 0; p < Dt; ++p) {
    const int d = d0 + p;
    const int dn = (d + 1 < DD) ? (d + 1) : d;  // clamp -> gx = 0 at d=159
    const float* fS = fb + (size_t)d * SLICE;
    const float* tS = tb + (size_t)d * SLICE;
    const float* fN = fb + (size_t)dn * SLICE;
    const float* tN = tb + (size_t)dn * SLICE;
    // per-phase loads: 6 f4 + 4 scalars, all independent
    const float4 Hf  = *(const float4*)(fS + r2 * WW + w);   // row r2 self (gy for r1)
    const float4 Ht  = *(const float4*)(tS + r2 * WW + w);
    const float4 D0f = *(const float4*)(fN + r0 * WW + w);   // next-d self r0
    const float4 D0t = *(const float4*)(tN + r0 * WW + w);
    const float4 D1f = *(const float4*)(fN + r1 * WW + w);   // next-d self r1
    const float4 D1t = *(const float4*)(tN + r1 * WW + w);
    const float d0fz = (fN + r0 * WW)[wn], d0tz = (tN + r0 * WW)[wn];
    const float d1fz = (fN + r1 * WW)[wn], d1tz = (tN + r1 * WW)[wn];

    float aH[24];
#pragma unroll
    for (int c = 0; c < 24; ++c) aH[c] = 0.0f;

    // ---- row r0: gx = D0-S0, gy = S1-S0, gz = shift(S0) ----
    {
      float xd = 0, xf = 0, xt = 0, yd = 0, yf = 0, yt = 0;
#pragma unroll
      for (int j = 0; j < 4; ++j) {
        const float f0 = ELEM(S0f, j), t0 = ELEM(S0t, j);
        const float gxf = ELEM(D0f, j) - f0, gxt = ELEM(D0t, j) - t0;
        const float gyf = ELEM(S1f, j) - f0, gyt = ELEM(S1t, j) - t0;
        const float fnx = (j < 3) ? ELEM(S0f, j + 1) : s0fz;
        const float tnx = (j < 3) ? ELEM(S0t, j + 1) : s0tz;
        const float gzf = fnx - f0, gzt = tnx - t0;
        xd += gxf * gxt; xf += gxf * gxf; xt += gxt * gxt;
        yd += gyf * gyt; yf += gyf * gyf; yt += gyt * gyt;
        aH[j * 6 + 0] += gxf * gxt; aH[j * 6 + 1] += gxf * gxf; aH[j * 6 + 2] += gxt * gxt;
        aH[j * 6 + 3] += gzf * gzt; aH[j * 6 + 4] += gzf * gzf; aH[j * 6 + 5] += gzt * gzt;
        aD[j * 6 + 0] += gyf * gyt; aD[j * 6 + 1] += gyf * gyf; aD[j * 6 + 2] += gyt * gyt;
        aD[j * 6 + 3] += gzf * gzt; aD[j * 6 + 4] += gzf * gzf; aD[j * 6 + 5] += gzt * gzt;
      }
      float* s = &sw[((g * 2 + 0) * 40 + l) * 7];
      s[0] = xd; s[1] = xf; s[2] = xt; s[3] = yd; s[4] = yf; s[5] = yt;
    }
    // ---- row r1: gx = D1-S1, gy = H-S1, gz = shift(S1) ----
    {
      float xd = 0, xf = 0, xt = 0, yd = 0, yf = 0, yt = 0;
#pragma unroll
      for (int j = 0; j < 4; ++j) {
        const float f0 = ELEM(S1f, j), t0 = ELEM(S1t, j);
        const float gxf = ELEM(D1f, j) - f0, gxt = ELEM(D1t, j) - t0;
        const float gyf = ELEM(Hf, j) - f0, gyt = ELEM(Ht, j) - t0;
        const float fnx = (j < 3) ? ELEM(S1f, j + 1) : s1fz;
        const float tnx = (j < 3) ? ELEM(S1t, j + 1) : s1tz;
        const float gzf = fnx - f0, gzt = tnx - t0;
        xd += gxf * gxt; xf += gxf * gxf; xt += gxt * gxt;
        yd += gyf * gyt; yf += gyf * gyf; yt += gyt * gyt;
        aH[j * 6 + 0] += gxf * gxt; aH[j * 6 + 1] += gxf * gxf; aH[j * 6 + 2] += gxt * gxt;
        aH[j * 6 + 3] += gzf * gzt; aH[j * 6 + 4] += gzf * gzf; aH[j * 6 + 5] += gzt * gzt;
        aD[(4 + j) * 6 + 0] += gyf * gyt; aD[(4 + j) * 6 + 1] += gyf * gyf; aD[(4 + j) * 6 + 2] += gyt * gyt;
        aD[(4 + j) * 6 + 3] += gzf * gzt; aD[(4 + j) * 6 + 4] += gzf * gzf; aD[(4 + j) * 6 + 5] += gzt * gzt;
      }
      float* s = &sw[((g * 2 + 1) * 40 + l) * 7];
      s[0] = xd; s[1] = xf; s[2] = xt; s[3] = yd; s[4] = yf; s[5] = yt;
    }
    // dump alongH partials
    {
      float* s2 = &sh[(g * 40 + l) * 25];
#pragma unroll
      for (int c = 0; c < 24; ++c) s2[c] = aH[c];
    }
    // register chain: next phase's selves are this phase's d-neighbors
    S0f = D0f; S0t = D0t; S1f = D1f; S1t = D1t;
    s0fz = d0fz; s0tz = d0tz; s1fz = d1fz; s1tz = d1tz;

    // ---- HOISTED pD stores: aD is final here in the last phase; issue the
    // 49 MB write burst before the barrier so it overlaps the final reduce.
    if (p == Dt - 1) {
#pragma unroll
      for (int r = 0; r < 2; ++r) {
        const int h = r0 + r;
#pragma unroll
        for (int cc = 0; cc < 6; ++cc) {
          float4 o;
          o.x = aD[(r * 4 + 0) * 6 + cc];
          o.y = aD[(r * 4 + 1) * 6 + cc];
          o.z = aD[(r * 4 + 2) * 6 + cc];
          o.w = aD[(r * 4 + 3) * 6 + cc];
          *(float4*)(pD + ((size_t)(dc * 6 + cc)) * NV + b * SLICE + h * 160 + 4 * l) = o;
        }
      }
    }
    __syncthreads();

    if (tid < 240) {
      // alongH reduce over 8 groups + coalesced f4 write to pH
      const int cc = tid / 40, ll = tid % 40;
      float v0 = 0, v1 = 0, v2 = 0, v3 = 0;
#pragma unroll
      for (int gg = 0; gg < 8; ++gg) {
        const float* q = &sh[(gg * 40 + ll) * 25];
        v0 += q[0 * 6 + cc]; v1 += q[1 * 6 + cc]; v2 += q[2 * 6 + cc]; v3 += q[3 * 6 + cc];
      }
      const int bd = b * DD + d;
      float4 o; o.x = v0; o.y = v1; o.z = v2; o.w = v3;
      *(float4*)(pH + ((size_t)(hc * 6 + cc)) * NV + bd * 160 + 4 * ll) = o;
    } else {
      // alongW reduce over 40 lanes: 96 tasks on 80 threads
      for (int k = tid - 240; k < HCS * 6; k += 80) {
        const int row = k / 6, c = k % 6;
        float s = 0.0f;
#pragma unroll 8
        for (int ll = 0; ll < 40; ++ll) s += sw[(row * 40 + ll) * 7 + c];
        red[row][c] = s;
      }
    }
    __syncthreads();
    if (tid < HCS) {
      const float cx = red[tid][0] / (fmaxf(sqrtf(red[tid][1]), EPS) * fmaxf(sqrtf(red[tid][2]), EPS));
      const float cy = red[tid][3] / (fmaxf(sqrtf(red[tid][4]), EPS) * fmaxf(sqrtf(red[tid][5]), EPS));
      accCos += cx + cy;
    }
  }

  if (tid < HCS) cpad[tid] = accCos;
  __syncthreads();
  if (tid == 0) {
    float s = 0.0f;
#pragma unroll
    for (int i = 0; i < HCS; ++i) s += cpad[i];
    atomicAdd(out, s * SCALE);
  }
}

// ---------------------------------------------------------------------------
// finalizeW: chunk-split parallel combine. Round-7's finalizeZ was occupancy-
// starved (200 blocks on 256 CUs). Here:
//  - blocks [0,100): alongH types 0,1 — one f4-task per thread, 10-chunk loop.
//  - blocks [100,500): alongD types 2,3 — each f4-task is split over 4
//    consecutive threads (10 chunks each), combined by intra-quad __shfl_xor
//    (masks 1,2 — never crosses a wave). 128000 threads total = 500 blocks.
// Same 61.4 MB read, ~2.7x the memory-level parallelism.
// ---------------------------------------------------------------------------
__global__ __launch_bounds__(256) void finalizeW(const float* __restrict__ P,
                                                 float* __restrict__ out) {
  const float* PH = P;
  const float* PD = P + (size_t)NHC * 6 * NV;
  float c = 0.0f;
  if (blockIdx.x < 100) {
    const int u = blockIdx.x * 256 + threadIdx.x;   // [0, 25600)
    const int type = u / NQ;                        // 0: gx-alongH, 1: gz-alongH
    const int vec4 = (u % NQ) * 4;
    float4 dot = {0, 0, 0, 0}, ff = {0, 0, 0, 0}, tt = {0, 0, 0, 0};
    const float* base = PH + (size_t)(type * 3) * NV + vec4;
#pragma unroll
    for (int ch = 0; ch < NHC; ++ch) {
      const float* q = base + (size_t)(ch * 6) * NV;
      const float4 a  = *(const float4*)(q);
      const float4 bb = *(const float4*)(q + (size_t)NV);
      const float4 cv = *(const float4*)(q + 2 * (size_t)NV);
      dot.x += a.x;  dot.y += a.y;  dot.z += a.z;  dot.w += a.w;
      ff.x += bb.x;  ff.y += bb.y;  ff.z += bb.z;  ff.w += bb.w;
      tt.x += cv.x;  tt.y += cv.y;  tt.z += cv.z;  tt.w += cv.w;
    }
    c = dot.x / (fmaxf(sqrtf(ff.x), EPS) * fmaxf(sqrtf(tt.x), EPS))
      + dot.y / (fmaxf(sqrtf(ff.y), EPS) * fmaxf(sqrtf(tt.y), EPS))
      + dot.z / (fmaxf(sqrtf(ff.z), EPS) * fmaxf(sqrtf(tt.z), EPS))
      + dot.w / (fmaxf(sqrtf(ff.w), EPS) * fmaxf(sqrtf(tt.w), EPS));
  } else {
    const int u = (blockIdx.x - 100) * 256 + threadIdx.x;  // [0, 102400)
    const int task = u >> 2, s = u & 3;
    const int type = task / NQ;                     // 0: gy-alongD, 1: gz-alongD
    const int vec4 = (task % NQ) * 4;
    float v[12];
#pragma unroll
    for (int i = 0; i < 12; ++i) v[i] = 0.0f;
    const float* base = PD + (size_t)(type * 3) * NV + vec4;
    for (int ch = s * 10; ch < s * 10 + 10; ++ch) {
      const float* q = base + (size_t)(ch * 6) * NV;
      const float4 a  = *(const float4*)(q);
      const float4 bb = *(const float4*)(q + (size_t)NV);
      const float4 cv = *(const float4*)(q + 2 * (size_t)NV);
      v[0] += a.x;  v[1] += a.y;  v[2]  += a.z;  v[3]  += a.w;
      v[4] += bb.x; v[5] += bb.y; v[6]  += bb.z; v[7]  += bb.w;
      v[8] += cv.x; v[9] += cv.y; v[10] += cv.z; v[11] += cv.w;
    }
    // intra-quad combine (splits are consecutive lanes: xor 1,2 stay in-wave)
#pragma unroll
    for (int i = 0; i < 12; ++i) {
      v[i] += __shfl_xor(v[i], 1);
      v[i] += __shfl_xor(v[i], 2);
    }
    if (s == 0) {
      c = v[0] / (fmaxf(sqrtf(v[4]), EPS) * fmaxf(sqrtf(v[8]),  EPS))
        + v[1] / (fmaxf(sqrtf(v[5]), EPS) * fmaxf(sqrtf(v[9]),  EPS))
        + v[2] / (fmaxf(sqrtf(v[6]), EPS) * fmaxf(sqrtf(v[10]), EPS))
        + v[3] / (fmaxf(sqrtf(v[7]), EPS) * fmaxf(sqrtf(v[11]), EPS));
    }
  }
#pragma unroll
  for (int m = 32; m >= 1; m >>= 1) c += __shfl_xor(c, m);
  __shared__ float part[4];
  if ((threadIdx.x & 63) == 0) part[threadIdx.x >> 6] = c;
  __syncthreads();
  if (threadIdx.x == 0) atomicAdd(out, (part[0] + part[1] + part[2] + part[3]) * SCALE);
}

extern "C" void kernel_launch(void* const* d_in, const int* in_sizes, int n_in,
                              void* d_out, int out_size, void* d_ws, size_t ws_size,
                              hipStream_t stream) {
  const float* fk = (const float*)d_in[0];
  const float* tr = (const float*)d_in[1];
  float* outp = (float*)d_out;
  float* P = (float*)d_ws;   // (NHC+NDC)*6*NV floats = 61.44 MB (== round-0 size)

  hipLaunchKernelGGL(zero_kernel, dim3(1), dim3(64), 0, stream, outp);
  hipLaunchKernelGGL(mainS, dim3(NBLK), dim3(NTHR), 0, stream, fk, tr, P, outp);
  hipLaunchKernelGGL(finalizeW, dim3(500), dim3(256), 0, stream, P, outp);
}